// Round 2
// 1048.305 us; speedup vs baseline: 1.8903x; 1.8903x over previous
//
#include <hip/hip_runtime.h>
#include <hip/hip_bf16.h>
#include <math.h>

// B=32, S=2048, D=128 causal attention.
// Inputs q,k,v FP32 (mask input ignored; causal by index).
// Outputs (a[B,S,S], out[B,S,D]) concatenated in d_out as FP32.
//
// Round-1 restructure:
//  - balanced pairing: block j handles q-tiles {j, 31-j} -> 512 uniform blocks
//  - lgkm-only barriers (a-stores drain in background, never serialized)
//  - K tile staged once per tile in LDS (bf16 row-major), shared by all waves
//  - a written directly from registers with nontemporal stores (ps buffer gone)

typedef __attribute__((ext_vector_type(8))) short bf16x8;   // 8 bf16 = 4 VGPRs
typedef __attribute__((ext_vector_type(4))) short bf16x4;   // 4 bf16 = 2 VGPRs
typedef __attribute__((ext_vector_type(4))) float f32x4;

#define MFMA(a, b, c) __builtin_amdgcn_mfma_f32_16x16x32_bf16((a), (b), (c), 0, 0, 0)

constexpr int   Sdim  = 2048;
constexpr int   Ddim  = 128;
constexpr int   BATCH = 32;
constexpr int   NT    = Sdim / 64;               // 32 q-tiles
constexpr float INV_SCALE = 0.08838834764831845f;  // 1/sqrt(128)
constexpr float NEG_BIG   = -1e30f;
constexpr int   KPAD = 8;   // kl row pad (bf16): stride 136*2=272B -> 2-way max on b128 reads
constexpr int   PADV = 8;   // vt row pad (bf16)
constexpr int   PADP = 8;   // pt row pad (bf16)

// Workgroup barrier that waits only on LDS ops (lgkmcnt), NOT on outstanding
// global stores/loads (vmcnt). Safe here: no inter-wave communication happens
// through global memory, only through LDS. Lets the 16KB/tile a-stores and
// zero-fill stores stay in flight across tiles instead of being drained at
// every __syncthreads (which emits s_waitcnt vmcnt(0)).
__device__ __forceinline__ void bar_lds() {
    asm volatile("s_waitcnt lgkmcnt(0)\n\ts_barrier" ::: "memory");
}

__device__ __forceinline__ bf16x8 pack8(const float* p) {
    float4 a = *(const float4*)p;
    float4 b = *(const float4*)(p + 4);
    union { __hip_bfloat16 h[8]; bf16x8 v; } u;
    u.h[0] = __float2bfloat16(a.x); u.h[1] = __float2bfloat16(a.y);
    u.h[2] = __float2bfloat16(a.z); u.h[3] = __float2bfloat16(a.w);
    u.h[4] = __float2bfloat16(b.x); u.h[5] = __float2bfloat16(b.y);
    u.h[6] = __float2bfloat16(b.z); u.h[7] = __float2bfloat16(b.w);
    return u.v;
}

__device__ __forceinline__ bf16x4 pack4(float4 a) {
    union { __hip_bfloat16 h[4]; bf16x4 v; } u;
    u.h[0] = __float2bfloat16(a.x); u.h[1] = __float2bfloat16(a.y);
    u.h[2] = __float2bfloat16(a.z); u.h[3] = __float2bfloat16(a.w);
    return u.v;
}

__global__ __launch_bounds__(256, 2)
void attn_kernel(const float* __restrict__ qg,
                 const float* __restrict__ kg,
                 const float* __restrict__ vg,
                 float* __restrict__ a_out,
                 float* __restrict__ o_out)
{
    const int jb   = blockIdx.x;        // pair index 0..15
    const int b    = blockIdx.y;
    const int tid  = threadIdx.x;
    const int wave = tid >> 6;          // each wave owns 16 q rows
    const int lane = tid & 63;
    const int li   = lane & 15;
    const int quad = lane >> 4;

    // LDS: 17408 + 18432 + 9216 = 45056 B -> 3 blocks/CU capacity (2 scheduled)
    __shared__ __hip_bfloat16 kl[64][Ddim + KPAD];  // K tile, row-major bf16
    __shared__ __hip_bfloat16 vt[Ddim][64 + PADV];  // V^T tile: vt[d][key]
    __shared__ __hip_bfloat16 pt[64][64 + PADP];    // P (bf16), wave-private rows

    const size_t boff = (size_t)b * Sdim * Ddim;
    const float* qb = qg + boff;
    const float* kb = kg + boff;
    const float* vb = vg + boff;
    float* ab = a_out + (size_t)b * Sdim * Sdim;

    // Balanced pairing: qi = jb then (NT-1 - jb); per-block work = 33 tiles/pass.
    for (int sel = 0; sel < 2; ++sel) {
        const int qi   = sel ? (NT - 1 - jb) : jb;
        const int q0   = qi * 64;
        const int row0 = q0 + wave * 16;

        // ---- Q fragments (A-layout: A[m=li][k=quad*8+j]), kept in regs ----
        bf16x8 qf[4];
        {
            const float* qrow = qb + (size_t)(row0 + li) * Ddim + quad * 8;
            #pragma unroll
            for (int ks = 0; ks < 4; ++ks)
                qf[ks] = pack8(qrow + ks * 32);
        }

        // ---- zero-fill fully-masked columns [64*(qi+1), S) for this wave's rows ----
        {
            const int c0  = (qi + 1) * 64;
            const int zc4 = (Sdim - c0) >> 2;     // float4 chunks per row
            const f32x4 z = (f32x4){0.f, 0.f, 0.f, 0.f};
            for (int rr = 0; rr < 16; ++rr) {
                f32x4* dst = (f32x4*)(ab + (size_t)(row0 + rr) * Sdim + c0);
                for (int c = lane; c < zc4; c += 64)
                    __builtin_nontemporal_store(z, dst + c);
            }
        }

        // =================== Pass 1: row max m and denom l ===================
        float m[4], l[4];
        #pragma unroll
        for (int r = 0; r < 4; ++r) { m[r] = NEG_BIG; l[r] = 0.f; }

        for (int kt = 0; kt <= qi; ++kt) {
            const int kv0 = kt * 64;

            bar_lds();   // kl reads of previous tile complete block-wide
            {            // stage K tile (64x128) as bf16 row-major, coalesced
                const float* kbt = kb + (size_t)kv0 * Ddim;
                int idx = tid;
                #pragma unroll
                for (int it = 0; it < 8; ++it, idx += 256) {
                    const int kk = idx >> 5;           // key row 0..63
                    const int d0 = (idx & 31) * 4;     // dim col
                    *(bf16x4*)&kl[kk][d0] = pack4(*(const float4*)(kbt + (size_t)kk * Ddim + d0));
                }
            }
            bar_lds();

            f32x4 acc[4];
            #pragma unroll
            for (int t = 0; t < 4; ++t) acc[t] = (f32x4){0.f, 0.f, 0.f, 0.f};
            #pragma unroll
            for (int t = 0; t < 4; ++t)
                #pragma unroll
                for (int ks = 0; ks < 4; ++ks) {
                    bf16x8 kf = *(const bf16x8*)&kl[t * 16 + li][ks * 32 + quad * 8];
                    acc[t] = MFMA(qf[ks], kf, acc[t]);
                }

            float s[4][4];
            #pragma unroll
            for (int t = 0; t < 4; ++t)
                #pragma unroll
                for (int r = 0; r < 4; ++r) {
                    float sv = acc[t][r] * INV_SCALE;
                    if (kt == qi) {
                        int col = kv0 + t * 16 + li;
                        int row = row0 + quad * 4 + r;
                        if (col > row) sv = NEG_BIG;
                    }
                    s[t][r] = sv;
                }

            #pragma unroll
            for (int r = 0; r < 4; ++r) {
                float tm = fmaxf(fmaxf(s[0][r], s[1][r]), fmaxf(s[2][r], s[3][r]));
                #pragma unroll
                for (int off = 1; off < 16; off <<= 1)
                    tm = fmaxf(tm, __shfl_xor(tm, off, 64));
                float mn    = fmaxf(m[r], tm);
                float alpha = __expf(m[r] - mn);   // 0 on first tile
                float se = __expf(s[0][r] - mn) + __expf(s[1][r] - mn)
                         + __expf(s[2][r] - mn) + __expf(s[3][r] - mn);
                #pragma unroll
                for (int off = 1; off < 16; off <<= 1)
                    se += __shfl_xor(se, off, 64);
                l[r] = l[r] * alpha + se;
                m[r] = mn;
            }
        }

        float invl[4];
        #pragma unroll
        for (int r = 0; r < 4; ++r) invl[r] = 1.0f / l[r];

        // =================== Pass 2: write a, accumulate O ===================
        f32x4 oacc[8];
        #pragma unroll
        for (int n = 0; n < 8; ++n) oacc[n] = (f32x4){0.f, 0.f, 0.f, 0.f};

        for (int kt = 0; kt <= qi; ++kt) {
            const int kv0 = kt * 64;

            bar_lds();   // kl/vt reads of previous tile complete block-wide
            {
                const float* kbt = kb + (size_t)kv0 * Ddim;
                const float* vbt = vb + (size_t)kv0 * Ddim;
                int idx = tid;
                #pragma unroll
                for (int it = 0; it < 8; ++it, idx += 256) {
                    const int kk = idx >> 5;
                    const int d0 = (idx & 31) * 4;
                    *(bf16x4*)&kl[kk][d0] = pack4(*(const float4*)(kbt + (size_t)kk * Ddim + d0));
                }
                idx = tid;
                #pragma unroll
                for (int it = 0; it < 8; ++it, idx += 256) {
                    const int kk = idx >> 5;
                    const int d0 = (idx & 31) * 4;
                    float4 vv = *(const float4*)(vbt + (size_t)kk * Ddim + d0);
                    vt[d0 + 0][kk] = __float2bfloat16(vv.x);
                    vt[d0 + 1][kk] = __float2bfloat16(vv.y);
                    vt[d0 + 2][kk] = __float2bfloat16(vv.z);
                    vt[d0 + 3][kk] = __float2bfloat16(vv.w);
                }
            }
            bar_lds();

            // recompute S tile from LDS K
            f32x4 acc[4];
            #pragma unroll
            for (int t = 0; t < 4; ++t) acc[t] = (f32x4){0.f, 0.f, 0.f, 0.f};
            #pragma unroll
            for (int t = 0; t < 4; ++t)
                #pragma unroll
                for (int ks = 0; ks < 4; ++ks) {
                    bf16x8 kf = *(const bf16x8*)&kl[t * 16 + li][ks * 32 + quad * 8];
                    acc[t] = MFMA(qf[ks], kf, acc[t]);
                }

            // p = exp(s-m)/l -> pt (bf16, wave-private, for PV) + direct nt store to a
            #pragma unroll
            for (int r = 0; r < 4; ++r) {
                const int rowL = wave * 16 + quad * 4 + r;
                float* dst = ab + (size_t)(q0 + rowL) * Sdim + kv0 + li;
                #pragma unroll
                for (int t = 0; t < 4; ++t) {
                    float sv = acc[t][r] * INV_SCALE;
                    if (kt == qi && (kv0 + t * 16 + li) > (q0 + rowL)) sv = NEG_BIG;
                    float p = __expf(sv - m[r]) * invl[r];
                    pt[rowL][t * 16 + li] = __float2bfloat16(p);
                    __builtin_nontemporal_store(p, dst + t * 16);
                }
            }

            // in-wave cross-lane pt exchange: ensure ds_writes landed before reads
            asm volatile("s_waitcnt lgkmcnt(0)" ::: "memory");

            // PV: O[16][128] += P[16][64] @ V[64][128]
            #pragma unroll
            for (int ks = 0; ks < 2; ++ks) {
                bf16x8 pf = *(const bf16x8*)&pt[wave * 16 + li][ks * 32 + quad * 8];
                #pragma unroll
                for (int nt = 0; nt < 8; ++nt) {
                    bf16x8 vf = *(const bf16x8*)&vt[nt * 16 + li][ks * 32 + quad * 8];
                    oacc[nt] = MFMA(pf, vf, oacc[nt]);
                }
            }
        }

        // ---- write O (fp32) ----
        float* ob = o_out + ((size_t)b * Sdim + row0) * Ddim;
        #pragma unroll
        for (int n = 0; n < 8; ++n)
            #pragma unroll
            for (int r = 0; r < 4; ++r)
                __builtin_nontemporal_store(oacc[n][r],
                    ob + (size_t)(quad * 4 + r) * Ddim + n * 16 + li);
    }
}

extern "C" void kernel_launch(void* const* d_in, const int* in_sizes, int n_in,
                              void* d_out, int out_size, void* d_ws, size_t ws_size,
                              hipStream_t stream)
{
    const float* q = (const float*)d_in[0];
    const float* k = (const float*)d_in[1];
    const float* v = (const float*)d_in[2];
    // d_in[3] = causal mask, ignored (reconstructed from indices)

    float* a = (float*)d_out;                             // [B,S,S]
    float* o = a + (size_t)BATCH * Sdim * Sdim;           // [B,S,D]

    dim3 grid(NT / 2, BATCH);   // 16 balanced pairs x 32 batches = 512 blocks
    attn_kernel<<<grid, 256, 0, stream>>>(q, k, v, a, o);
}

// Round 3
// 1042.564 us; speedup vs baseline: 1.9007x; 1.0055x over previous
//
#include <hip/hip_runtime.h>
#include <hip/hip_bf16.h>
#include <math.h>

// B=32, S=2048, D=128 causal attention.
// Inputs q,k,v FP32 (mask input ignored; causal by index).
// Outputs (a[B,S,S], out[B,S,D]) concatenated in d_out as FP32.
//
// Round-2:
//  - T14 register prefetch: global loads for tile kt+1 issued at start of
//    compute(kt); consumed by ds_write at next bar. HBM latency hidden.
//  - XCD-clustered 1-D grid: all 16 blocks of a batch on one XCD (L2 reuse).
//  - s_setprio(1) around MFMA clusters.

typedef __attribute__((ext_vector_type(8))) short bf16x8;   // 8 bf16 = 4 VGPRs
typedef __attribute__((ext_vector_type(4))) short bf16x4;   // 4 bf16 = 2 VGPRs
typedef __attribute__((ext_vector_type(4))) float f32x4;

#define MFMA(a, b, c) __builtin_amdgcn_mfma_f32_16x16x32_bf16((a), (b), (c), 0, 0, 0)

constexpr int   Sdim  = 2048;
constexpr int   Ddim  = 128;
constexpr int   BATCH = 32;
constexpr int   NT    = Sdim / 64;               // 32 q-tiles
constexpr float INV_SCALE = 0.08838834764831845f;  // 1/sqrt(128)
constexpr float NEG_BIG   = -1e30f;
constexpr int   KPAD = 8;
constexpr int   PADV = 8;
constexpr int   PADP = 8;

// Barrier that waits only on LDS ops (lgkmcnt), not outstanding global
// stores/loads. All inter-wave communication is through LDS; a-stores and
// prefetch loads stay in flight across barriers.
__device__ __forceinline__ void bar_lds() {
    asm volatile("s_waitcnt lgkmcnt(0)\n\ts_barrier" ::: "memory");
}

__device__ __forceinline__ bf16x8 pack8(const float* p) {
    float4 a = *(const float4*)p;
    float4 b = *(const float4*)(p + 4);
    union { __hip_bfloat16 h[8]; bf16x8 v; } u;
    u.h[0] = __float2bfloat16(a.x); u.h[1] = __float2bfloat16(a.y);
    u.h[2] = __float2bfloat16(a.z); u.h[3] = __float2bfloat16(a.w);
    u.h[4] = __float2bfloat16(b.x); u.h[5] = __float2bfloat16(b.y);
    u.h[6] = __float2bfloat16(b.z); u.h[7] = __float2bfloat16(b.w);
    return u.v;
}

__device__ __forceinline__ bf16x4 pack4(float4 a) {
    union { __hip_bfloat16 h[4]; bf16x4 v; } u;
    u.h[0] = __float2bfloat16(a.x); u.h[1] = __float2bfloat16(a.y);
    u.h[2] = __float2bfloat16(a.z); u.h[3] = __float2bfloat16(a.w);
    return u.v;
}

__global__ __launch_bounds__(256, 2)
void attn_kernel(const float* __restrict__ qg,
                 const float* __restrict__ kg,
                 const float* __restrict__ vg,
                 float* __restrict__ a_out,
                 float* __restrict__ o_out)
{
    // XCD-clustered decode: flat = (b&7) + 8*(jb + 16*(b>>3))
    // => flat % 8 == b % 8, so all 16 blocks of a batch share an XCD.
    const int flat = blockIdx.x;
    const int xcd  = flat & 7;
    const int rdec = flat >> 3;          // 0..63
    const int jb   = rdec & 15;          // pair index 0..15
    const int b    = xcd + 8 * (rdec >> 4);

    const int tid  = threadIdx.x;
    const int wave = tid >> 6;
    const int lane = tid & 63;
    const int li   = lane & 15;
    const int quad = lane >> 4;

    __shared__ __hip_bfloat16 kl[64][Ddim + KPAD];  // K tile, row-major bf16
    __shared__ __hip_bfloat16 vt[Ddim][64 + PADV];  // V^T tile: vt[d][key]
    __shared__ __hip_bfloat16 pt[64][64 + PADP];    // P (bf16), wave-private rows

    const size_t boff = (size_t)b * Sdim * Ddim;
    const float* qb = qg + boff;
    const float* kb = kg + boff;
    const float* vb = vg + boff;
    float* ab = a_out + (size_t)b * Sdim * Sdim;

    // per-thread staging geometry (same for loads and ds_writes)
    int skk[8], sd0[8];
    #pragma unroll
    for (int it = 0; it < 8; ++it) {
        const int idx = tid + it * 256;
        skk[it] = idx >> 5;              // key row 0..63
        sd0[it] = (idx & 31) * 4;        // dim col
    }

    for (int sel = 0; sel < 2; ++sel) {
        const int qi   = sel ? (NT - 1 - jb) : jb;
        const int q0   = qi * 64;
        const int row0 = q0 + wave * 16;

        // ---- Q fragments (A-layout), kept in regs ----
        bf16x8 qf[4];
        {
            const float* qrow = qb + (size_t)(row0 + li) * Ddim + quad * 8;
            #pragma unroll
            for (int ks = 0; ks < 4; ++ks)
                qf[ks] = pack8(qrow + ks * 32);
        }

        // ---- zero-fill fully-masked columns [64*(qi+1), S) ----
        {
            const int c0  = (qi + 1) * 64;
            const int zc4 = (Sdim - c0) >> 2;
            const f32x4 z = (f32x4){0.f, 0.f, 0.f, 0.f};
            for (int rr = 0; rr < 16; ++rr) {
                f32x4* dst = (f32x4*)(ab + (size_t)(row0 + rr) * Sdim + c0);
                for (int c = lane; c < zc4; c += 64)
                    __builtin_nontemporal_store(z, dst + c);
            }
        }

        // =================== Pass 1: row max m and denom l ===================
        float m[4], l[4];
        #pragma unroll
        for (int r = 0; r < 4; ++r) { m[r] = NEG_BIG; l[r] = 0.f; }

        float4 kpre[8];
        #pragma unroll
        for (int it = 0; it < 8; ++it)
            kpre[it] = *(const float4*)(kb + (size_t)skk[it] * Ddim + sd0[it]);

        for (int kt = 0; kt <= qi; ++kt) {
            bar_lds();   // kl reads of previous tile complete block-wide
            #pragma unroll
            for (int it = 0; it < 8; ++it)
                *(bf16x4*)&kl[skk[it]][sd0[it]] = pack4(kpre[it]);
            bar_lds();

            // prefetch next K tile into regs (latency hides under compute)
            if (kt < qi) {
                const float* kbt = kb + (size_t)(kt + 1) * 64 * Ddim;
                #pragma unroll
                for (int it = 0; it < 8; ++it)
                    kpre[it] = *(const float4*)(kbt + (size_t)skk[it] * Ddim + sd0[it]);
            }

            const int kv0 = kt * 64;
            f32x4 acc[4];
            #pragma unroll
            for (int t = 0; t < 4; ++t) acc[t] = (f32x4){0.f, 0.f, 0.f, 0.f};
            __builtin_amdgcn_s_setprio(1);
            #pragma unroll
            for (int t = 0; t < 4; ++t)
                #pragma unroll
                for (int ks = 0; ks < 4; ++ks) {
                    bf16x8 kf = *(const bf16x8*)&kl[t * 16 + li][ks * 32 + quad * 8];
                    acc[t] = MFMA(qf[ks], kf, acc[t]);
                }
            __builtin_amdgcn_s_setprio(0);

            float s[4][4];
            #pragma unroll
            for (int t = 0; t < 4; ++t)
                #pragma unroll
                for (int r = 0; r < 4; ++r) {
                    float sv = acc[t][r] * INV_SCALE;
                    if (kt == qi) {
                        int col = kv0 + t * 16 + li;
                        int row = row0 + quad * 4 + r;
                        if (col > row) sv = NEG_BIG;
                    }
                    s[t][r] = sv;
                }

            #pragma unroll
            for (int r = 0; r < 4; ++r) {
                float tm = fmaxf(fmaxf(s[0][r], s[1][r]), fmaxf(s[2][r], s[3][r]));
                #pragma unroll
                for (int off = 1; off < 16; off <<= 1)
                    tm = fmaxf(tm, __shfl_xor(tm, off, 64));
                float mn    = fmaxf(m[r], tm);
                float alpha = __expf(m[r] - mn);
                float se = __expf(s[0][r] - mn) + __expf(s[1][r] - mn)
                         + __expf(s[2][r] - mn) + __expf(s[3][r] - mn);
                #pragma unroll
                for (int off = 1; off < 16; off <<= 1)
                    se += __shfl_xor(se, off, 64);
                l[r] = l[r] * alpha + se;
                m[r] = mn;
            }
        }

        float invl[4];
        #pragma unroll
        for (int r = 0; r < 4; ++r) invl[r] = 1.0f / l[r];

        // =================== Pass 2: write a, accumulate O ===================
        f32x4 oacc[8];
        #pragma unroll
        for (int n = 0; n < 8; ++n) oacc[n] = (f32x4){0.f, 0.f, 0.f, 0.f};

        float4 vpre[8];
        #pragma unroll
        for (int it = 0; it < 8; ++it) {
            kpre[it] = *(const float4*)(kb + (size_t)skk[it] * Ddim + sd0[it]);
            vpre[it] = *(const float4*)(vb + (size_t)skk[it] * Ddim + sd0[it]);
        }

        for (int kt = 0; kt <= qi; ++kt) {
            const int kv0 = kt * 64;

            bar_lds();   // kl/vt reads of previous tile complete block-wide
            #pragma unroll
            for (int it = 0; it < 8; ++it)
                *(bf16x4*)&kl[skk[it]][sd0[it]] = pack4(kpre[it]);
            #pragma unroll
            for (int it = 0; it < 8; ++it) {
                const int kk = skk[it], d0 = sd0[it];
                float4 vv = vpre[it];
                vt[d0 + 0][kk] = __float2bfloat16(vv.x);
                vt[d0 + 1][kk] = __float2bfloat16(vv.y);
                vt[d0 + 2][kk] = __float2bfloat16(vv.z);
                vt[d0 + 3][kk] = __float2bfloat16(vv.w);
            }
            bar_lds();

            // prefetch next K,V tiles into regs
            if (kt < qi) {
                const float* kbt = kb + (size_t)(kt + 1) * 64 * Ddim;
                const float* vbt = vb + (size_t)(kt + 1) * 64 * Ddim;
                #pragma unroll
                for (int it = 0; it < 8; ++it) {
                    kpre[it] = *(const float4*)(kbt + (size_t)skk[it] * Ddim + sd0[it]);
                    vpre[it] = *(const float4*)(vbt + (size_t)skk[it] * Ddim + sd0[it]);
                }
            }

            // recompute S tile from LDS K
            f32x4 acc[4];
            #pragma unroll
            for (int t = 0; t < 4; ++t) acc[t] = (f32x4){0.f, 0.f, 0.f, 0.f};
            __builtin_amdgcn_s_setprio(1);
            #pragma unroll
            for (int t = 0; t < 4; ++t)
                #pragma unroll
                for (int ks = 0; ks < 4; ++ks) {
                    bf16x8 kf = *(const bf16x8*)&kl[t * 16 + li][ks * 32 + quad * 8];
                    acc[t] = MFMA(qf[ks], kf, acc[t]);
                }
            __builtin_amdgcn_s_setprio(0);

            // p = exp(s-m)/l -> pt (bf16, wave-private rows) + direct nt store to a
            #pragma unroll
            for (int r = 0; r < 4; ++r) {
                const int rowL = wave * 16 + quad * 4 + r;
                float* dst = ab + (size_t)(q0 + rowL) * Sdim + kv0 + li;
                #pragma unroll
                for (int t = 0; t < 4; ++t) {
                    float sv = acc[t][r] * INV_SCALE;
                    if (kt == qi && (kv0 + t * 16 + li) > (q0 + rowL)) sv = NEG_BIG;
                    float p = __expf(sv - m[r]) * invl[r];
                    pt[rowL][t * 16 + li] = __float2bfloat16(p);
                    __builtin_nontemporal_store(p, dst + t * 16);
                }
            }

            // in-wave cross-lane pt exchange: ds_writes landed before reads
            asm volatile("s_waitcnt lgkmcnt(0)" ::: "memory");

            // PV: O[16][128] += P[16][64] @ V[64][128]
            __builtin_amdgcn_s_setprio(1);
            #pragma unroll
            for (int ks = 0; ks < 2; ++ks) {
                bf16x8 pf = *(const bf16x8*)&pt[wave * 16 + li][ks * 32 + quad * 8];
                #pragma unroll
                for (int nt = 0; nt < 8; ++nt) {
                    bf16x8 vf = *(const bf16x8*)&vt[nt * 16 + li][ks * 32 + quad * 8];
                    oacc[nt] = MFMA(pf, vf, oacc[nt]);
                }
            }
            __builtin_amdgcn_s_setprio(0);
        }

        // ---- write O (fp32) ----
        float* ob = o_out + ((size_t)b * Sdim + row0) * Ddim;
        #pragma unroll
        for (int n = 0; n < 8; ++n)
            #pragma unroll
            for (int r = 0; r < 4; ++r)
                __builtin_nontemporal_store(oacc[n][r],
                    ob + (size_t)(quad * 4 + r) * Ddim + n * 16 + li);
    }
}

extern "C" void kernel_launch(void* const* d_in, const int* in_sizes, int n_in,
                              void* d_out, int out_size, void* d_ws, size_t ws_size,
                              hipStream_t stream)
{
    const float* q = (const float*)d_in[0];
    const float* k = (const float*)d_in[1];
    const float* v = (const float*)d_in[2];
    // d_in[3] = causal mask, ignored (reconstructed from indices)

    float* a = (float*)d_out;                             // [B,S,S]
    float* o = a + (size_t)BATCH * Sdim * Sdim;           // [B,S,D]

    attn_kernel<<<dim3(512), 256, 0, stream>>>(q, k, v, a, o);
}